// Round 9
// baseline (168.821 us; speedup 1.0000x reference)
//
#include <hip/hip_runtime.h>
#include <stdint.h>

#define NT 4
#define PP 100
#define TT_BYTES (4ull * 100 * 100 * 1024)   // 40,960,000 B for tT in d_ws

// tT layout per combo (tab,i0,i1), 1 KB, AB-MAJOR (MFMA A-frag friendly):
//   bf16 t[ab][s] at byte ab*64 + s*2. Lane l's A-frag = slice bytes
//   (l&15)*64 + (l>>4)*16 -- and a linear lane*16 DMA dump preserves slice
//   bytes, so ds_read_b128 at that offset yields the frag.
// c2a layout (after tT in d_ws), B-frag layout, 102,400 B:
//   dword ((tab*100+i2)*4 + n)*16 + sgrp*4 + jp packs
//   lo = bf16 c2[s=sgrp*8+2jp][n], hi = bf16 c2[s+1][n]  (n 0..3)
//   uint4 chunk index within 256 B slice: n*4 + sgrp.

typedef __attribute__((ext_vector_type(8))) short short8;
typedef __attribute__((ext_vector_type(4))) float floatx4;
union U4S8 { uint4 u; short8 s; };

#define GLOAD_LDS16(g, l) __builtin_amdgcn_global_load_lds(                  \
    (const __attribute__((address_space(1))) void*)(g),                      \
    (__attribute__((address_space(3))) void*)(l), 16, 0, 0)

__device__ __forceinline__ uint32_t f2bf(float f) {
    union { float f; uint32_t u; } v; v.f = f;
    uint32_t u = v.u;
    return (u + 0x7fffu + ((u >> 16) & 1u)) >> 16;   // RNE to bf16
}

// ---------------- Phase 1: t = c0 @ c1  (+ fused c2 pack in blocks 0..199) ----
// grid: 4 tab * 100 i1 * 7 chunks(16 i0) = 2800 blocks, 128 threads.
// thread (u 0..7, sg 0..15): 2 i0 (2u,2u+1), s-pair (2sg,2sg+1), all 16 ab.
__global__ __launch_bounds__(128)
void tt_phase1(const float* __restrict__ c0g, const float* __restrict__ c1g,
               const float* __restrict__ c2g, unsigned short* __restrict__ tT,
               uint32_t* __restrict__ c2a) {
    __shared__ float c1s[32 * 128];   // [r][b*32+s]
    __shared__ float c0t[16 * 136];   // [i0l][r*4+a], stride 136 -> 16B-aligned b128

    int blk = blockIdx.x;
    int tid = threadIdx.x;

    // fused c2 pack (B-frag layout): 200 blocks x 128 threads = 25600 dwords
    if (blk < 200) {
        int t = blk * 128 + tid;
        int jp = t & 3, sgrp = (t >> 2) & 3, nn = (t >> 4) & 3, rest = t >> 6;
        int i2 = rest % PP, tb = rest / PP;
        const float* src = c2g + (size_t)(tb * PP + i2) * 128;
        int s = sgrp * 8 + 2 * jp;
        c2a[t] = f2bf(src[s * 4 + nn]) | (f2bf(src[(s + 1) * 4 + nn]) << 16);
    }

    int tab   = blk / 700;
    int rem   = blk % 700;
    int i1    = rem / 7;
    int chunk = rem % 7;
    int i0_base = chunk * 16;

    const float4* c1p = (const float4*)(c1g + (size_t)(tab * PP + i1) * 4096);
    float4* c1v = (float4*)c1s;
    #pragma unroll
    for (int it = 0; it < 8; ++it) c1v[tid + 128 * it] = c1p[tid + 128 * it];

    #pragma unroll
    for (int it = 0; it < 16; ++it) {
        int f = tid + 128 * it;          // 0..2047
        int i0l = f >> 7;
        int x   = f & 127;               // a*32 + r
        int a = x >> 5, r = x & 31;
        int i0 = i0_base + i0l; if (i0 > PP - 1) i0 = PP - 1;
        c0t[i0l * 136 + r * 4 + a] = c0g[(size_t)(tab * PP + i0) * 128 + x];
    }
    __syncthreads();

    int u  = tid >> 4;                   // 0..7
    int sg = tid & 15;

    float acc[2][2][16];                 // [i0 sel][e (s parity)][ab]
    #pragma unroll
    for (int ii = 0; ii < 2; ++ii)
        #pragma unroll
        for (int e = 0; e < 2; ++e)
            #pragma unroll
            for (int q = 0; q < 16; ++q) acc[ii][e][q] = 0.f;

    #pragma unroll 4
    for (int r = 0; r < 32; ++r) {
        float4 av0 = *(const float4*)&c0t[(2 * u) * 136 + r * 4];
        float4 av1 = *(const float4*)&c0t[(2 * u + 1) * 136 + r * 4];
        const float* a0 = (const float*)&av0;
        const float* a1 = (const float*)&av1;
        #pragma unroll
        for (int b = 0; b < 4; ++b) {
            float2 bv = *(const float2*)&c1s[r * 128 + b * 32 + 2 * sg];
            #pragma unroll
            for (int a = 0; a < 4; ++a) {
                acc[0][0][a * 4 + b] += a0[a] * bv.x;
                acc[0][1][a * 4 + b] += a0[a] * bv.y;
                acc[1][0][a * 4 + b] += a1[a] * bv.x;
                acc[1][1][a * 4 + b] += a1[a] * bv.y;
            }
        }
    }

    // store ab-major: dword (t[ab][2sg], t[ab][2sg+1]) at dword index ab*16 + sg
    #pragma unroll
    for (int ii = 0; ii < 2; ++ii) {
        int i0 = i0_base + 2 * u + ii;
        if (i0 >= PP) continue;
        size_t combo = (size_t)tab * 10000 + (size_t)i0 * 100 + (size_t)i1;
        uint32_t* bp = (uint32_t*)((char*)tT + combo * 1024) + sg;
        #pragma unroll
        for (int ab = 0; ab < 16; ++ab)
            bp[ab * 16] = f2bf(acc[ii][0][ab]) | (f2bf(acc[ii][1][ab]) << 16);
    }
}

// ---------------- Phase 2: DMA-staged MFMA gather-contract-pool ----------------
// 1 wave per bag, 4 waves/block (all same table). A-slices arrive via
// global_load_lds (1 KB/instr, zero VGPR residency -> all 8 in flight per
// batch); the block's whole packed-c2 table (25.6 KB) is LDS-staged once, so
// B-frags are conflict-free broadcast ds_read_b128. 16 MFMA/wave; pooling
// free in the C frag; round-6 LDS epilogue (256 B contiguous store/bag).
__global__ __launch_bounds__(256)
void tt_phase2(const int* __restrict__ indices, const int* __restrict__ offsets,
               const unsigned short* __restrict__ tT, const uint32_t* __restrict__ c2a,
               float* __restrict__ out, int bags_per_table, int B) {
    __shared__ uint4 c2s[1600];        // table's packed c2, 25600 B
    __shared__ char  aslab[4][8192];   // per-wave A staging (8 slices/batch)
    __shared__ float obuf[4][64];

    int tid  = threadIdx.x;
    int lane = tid & 63, wv = tid >> 6;
    int bag  = blockIdx.x * 4 + wv;
    if (bag >= B) return;
    int tab  = (int)(((long)blockIdx.x * 4) / bags_per_table);

    // stage this table's packed c2 into LDS (1600 uint4)
    const uint4* csrc = (const uint4*)c2a + (size_t)tab * 1600;
    #pragma unroll
    for (int it = 0; it < 7; ++it) {
        int i = tid + 256 * it;
        if (i < 1600) c2s[i] = csrc[i];
    }

    // load + decode all 16 lookup indices (wave-broadcast 64 B)
    int start = offsets[bag];
    uint32_t code[16];
    {
        const int4* ip = (const int4*)&indices[start];
        int4 v0 = ip[0], v1 = ip[1], v2 = ip[2], v3 = ip[3];
        int raw[16] = { v0.x, v0.y, v0.z, v0.w, v1.x, v1.y, v1.z, v1.w,
                        v2.x, v2.y, v2.z, v2.w, v3.x, v3.y, v3.z, v3.w };
        #pragma unroll
        for (int j = 0; j < 16; ++j) {
            uint32_t idx = (uint32_t)raw[j];
            uint32_t i0 = idx / 10000u;
            uint32_t r1 = idx - i0 * 10000u;
            uint32_t i1 = r1 / 100u;
            uint32_t i2 = r1 - i1 * 100u;
            code[j] = (i0 * 100u + i1) * 128u + i2;   // combo<<7 | i2
        }
    }

    const char* tbl = (const char*)tT + (size_t)tab * 10000u * 1024u
                                      + (size_t)lane * 16u;

    // batch 0: 8 slice DMAs (1 KB each), in flight across the barrier
    #pragma unroll
    for (int j = 0; j < 8; ++j)
        GLOAD_LDS16(tbl + (size_t)(code[j] >> 7) * 1024u, &aslab[wv][j * 1024]);

    __syncthreads();   // c2s ready; barrier's vmcnt(0) drain also completes DMAs

    int n = lane & 15, quad = lane >> 4;
    int aoff = n * 64 + quad * 16;       // A-frag byte offset in slice
    int boff = (n & 3) * 4 + quad;       // B-frag uint4 chunk in 256 B slice

    floatx4 acc = {0.f, 0.f, 0.f, 0.f};
    #pragma unroll
    for (int j = 0; j < 8; ++j) {
        U4S8 a, b;
        a.u = *(const uint4*)&aslab[wv][j * 1024 + aoff];
        b.u = c2s[(code[j] & 127u) * 16u + boff];
        acc = __builtin_amdgcn_mfma_f32_16x16x32_bf16(a.s, b.s, acc, 0, 0, 0);
    }

    // ensure batch-0 A-frags are in registers before overwriting the slab
    __asm__ volatile("s_waitcnt lgkmcnt(0)" ::: "memory");

    #pragma unroll
    for (int j = 8; j < 16; ++j)
        GLOAD_LDS16(tbl + (size_t)(code[j] >> 7) * 1024u, &aslab[wv][(j - 8) * 1024]);
    __asm__ volatile("s_waitcnt vmcnt(0)" ::: "memory");

    #pragma unroll
    for (int j = 8; j < 16; ++j) {
        U4S8 a, b;
        a.u = *(const uint4*)&aslab[wv][(j - 8) * 1024 + aoff];
        b.u = c2s[(code[j] & 127u) * 16u + boff];
        acc = __builtin_amdgcn_mfma_f32_16x16x32_bf16(a.s, b.s, acc, 0, 0, 0);
    }

    // C/D layout: col = lane&15 (= c, live c<4), row = quad*4 + reg (= ab).
    if (n < 4) {
        #pragma unroll
        for (int r = 0; r < 4; ++r)
            obuf[wv][quad * 16 + r * 4 + n] = acc[r];
    }
    __asm__ volatile("s_waitcnt lgkmcnt(0)" ::: "memory");   // same-wave handoff
    if (lane < 16) {
        float4 v = *(const float4*)&obuf[wv][lane * 4];
        ((float4*)(out + (size_t)bag * 64))[lane] = v;
    }
}

extern "C" void kernel_launch(void* const* d_in, const int* in_sizes, int n_in,
                              void* d_out, int out_size, void* d_ws, size_t ws_size,
                              hipStream_t stream) {
    const int*   indices = (const int*)d_in[0];
    const int*   offsets = (const int*)d_in[1];
    const float* c0      = (const float*)d_in[2];
    const float* c1      = (const float*)d_in[3];
    const float* c2      = (const float*)d_in[4];
    float* out = (float*)d_out;

    int B = in_sizes[1] - 1;              // 32768 bags
    int bags_per_table = B / NT;          // 8192

    unsigned short* tT  = (unsigned short*)d_ws;
    uint32_t*       c2a = (uint32_t*)((char*)d_ws + TT_BYTES);   // +100 KB

    tt_phase1<<<dim3(NT * PP * 7), dim3(128), 0, stream>>>(c0, c1, c2, tT, c2a);
    tt_phase2<<<dim3((B + 3) / 4), dim3(256), 0, stream>>>(indices, offsets, tT, c2a, out,
                                                           bags_per_table, B);
}